// Round 8
// baseline (739.498 us; speedup 1.0000x reference)
//
#include <hip/hip_runtime.h>
#include <math.h>

#define B_ 64
#define T_ 1024
#define D_ 512
#define U_ 1024
#define NTILE 8

typedef __bf16 bf16x8 __attribute__((ext_vector_type(8)));
typedef float f32x16 __attribute__((ext_vector_type(16)));
typedef unsigned int u32;

// tanh(x) given x2 = 2x, pre-clamped: 1 - 2/(1+e^{x2}). Sign-correct both
// tails; clamp +-18 keeps tanh exact to <1e-7. 3 VALU + 2 trans.
__device__ __forceinline__ float tanh_from_x2(float x2) {
    const float xc = __builtin_amdgcn_fmed3f(x2, -18.f, 18.f);
    const float e  = __expf(xc);
    const float r  = __builtin_amdgcn_rcpf(e + 1.0f);
    return fmaf(-2.0f, r, 1.0f);
}

// pack two f32 -> two bf16 (round-half-up): 2 adds + 1 v_perm
__device__ __forceinline__ u32 f2bf_pk(float lo, float hi) {
    u32 a = __float_as_uint(lo) + 0x8000u;
    u32 b = __float_as_uint(hi) + 0x8000u;
    return __builtin_amdgcn_perm(b, a, 0x07060302u);
}

// K_prep: blocks [0,256): W1 [D][U] fp32 -> W1F in MFMA-fragment order:
//   frag=(ut*16+kt)*2+ks holds B-frag for u-tile ut (32 u), k=kt*32+ks*16;
//   slot (frag,lane) = 8 bf16: u=ut*32+(lane&31), k0=kt*32+ks*16+(lane>>5)*8.
// blocks [256,512): ph[b][u] = hidden·W2 + W2_b + W1_b; also zero out_ctx
// for the atomic accumulation in ctx_kernel.
__global__ __launch_bounds__(256) void prep_kernel(
    const float* __restrict__ W1, const float* __restrict__ hidden,
    const float* __restrict__ W2, const float* __restrict__ W2b,
    const float* __restrict__ W1b,
    unsigned short* __restrict__ W1F, float* __restrict__ ph,
    float* __restrict__ ctx0) {
    if (blockIdx.x < 256) {
        const int gid  = blockIdx.x * 256 + threadIdx.x;  // 0..65535
        const int lane = gid & 63;
        const int frag = gid >> 6;                        // 0..1023
        const int ks = frag & 1;
        const int kt = (frag >> 1) & 15;
        const int ut = frag >> 5;
        const int u  = ut * 32 + (lane & 31);
        const int k0 = kt * 32 + ks * 16 + (lane >> 5) * 8;
        float f[8];
#pragma unroll
        for (int j = 0; j < 8; ++j) f[j] = W1[(size_t)(k0 + j) * U_ + u];
        uint4 w;
        w.x = f2bf_pk(f[0], f[1]);
        w.y = f2bf_pk(f[2], f[3]);
        w.z = f2bf_pk(f[4], f[5]);
        w.w = f2bf_pk(f[6], f[7]);
        *(uint4*)&W1F[(size_t)gid * 8] = w;
    } else {
        const int bx = blockIdx.x - 256;
        const int zi = bx * 256 + (int)threadIdx.x;
        if (zi < B_ * D_) ctx0[zi] = 0.f;
        const int u  = (bx & 3) * 256 + threadIdx.x;
        const int b  = bx >> 2;
        const float* h = hidden + b * D_;
        float acc = 0.f;
#pragma unroll 8
        for (int d = 0; d < D_; ++d) acc = fmaf(h[d], W2[(size_t)d * U_ + u], acc);
        ph[b * U_ + u] = acc + W2b[u] + W1b[u];
    }
}

// K2: fused bf16 32x32x16-MFMA GEMM + tanh + V-dot, SOFTWARE-PIPELINED.
// v8: r7 was latency-bound (r6->r7: LDS reads halved, conflicts 1.08M->16K,
// dur UNCHANGED — the serial stage->barrier->Kloop->epilogue chain is the
// cost, A-feed ~13K cyc/tile issued as an unhidden burst). Fix: each block
// owns 8 sequential 32-row t-tiles with As[2] ping-pong; tile i+1's global
// loads are issued in 2 half-chunks before/inside tile i's K-loop (reg cap),
// ds_written to the idle buffer, ONE barrier per tile. HBM feed hides under
// MFMA+tanh and vice versa. Grid 512 = 4tg x 2uh x 64b, exactly 2 blocks/CU,
// uh-pair shares A via L2 (proven: FETCH~139MB). Waves: 4 x (32t x 128u).
// Regs ~200 of the 256-class (launch_bounds(256,2)); r3 spill sentinel =
// WRITE_SIZE explosion.
__global__ __launch_bounds__(256, 2) void logits_mfma_kernel(
    const float* __restrict__ feat,          // [B,T,D] fp32
    const unsigned short* __restrict__ W1F,  // fragment-order bf16
    const float* __restrict__ ph,            // [B,U] biases folded
    const float* __restrict__ Vw,            // [U]
    float* __restrict__ lpart) {             // [8][B][T] partials
    __shared__ __align__(16) char As[2][32768];  // per buf: 16 panels x 32 rows x 64 B

    const int tid  = threadIdx.x;
    const int gx   = blockIdx.x;        // uh fastest: A-sharing pair co-dispatch
    const int uh   = gx & 1;
    const int tg   = gx >> 1;           // 0..3 (256-t group)
    const int b    = blockIdx.y;
    const int lane = tid & 63;
    const int widx = tid >> 6;          // 0..3
    const int l31 = lane & 31, g = lane >> 5;

    // staging geometry: 32 rows x 8 threads/row, 8 16B-slots per thread
    const int r  = tid >> 3;            // 0..31
    const int s0 = tid & 7;
    const int xr = (r >> 2) & 3;
    const float* asrc = feat + ((size_t)(b * T_ + tg * (32 * NTILE) + r)) * D_;

    // B frag base for the wave's u-strip: u0 = uh*512 + widx*128 (4 u-tiles)
    const char* bfbase = (const char*)W1F +
                         (size_t)(uh * 16 + widx * 4) * 32768 + lane * 16;

    // biases/V preloaded once (same u's for every tile)
    float phv2[4], vwv[4];
#pragma unroll
    for (int nt = 0; nt < 4; ++nt) {
        const int u = uh * 512 + widx * 128 + nt * 32 + l31;
        phv2[nt] = 2.0f * ph[b * U_ + u];
        vwv[nt]  = Vw[u];
    }

    float4 sr[8];   // staging regs: ONE half-chunk (8 float4 = 128 B) at a time
    auto issueA = [&](int i, int h) {
#pragma unroll
        for (int j = 0; j < 4; ++j) {
            const int s = s0 + 8 * (4 * h + j);
            const float* p = asrc + (size_t)i * 32 * D_ + s * 8;
            sr[2 * j]     = *(const float4*)p;
            sr[2 * j + 1] = *(const float4*)(p + 4);
        }
    };
    auto writeA = [&](int i, int h) {
        char* dbuf = As[i & 1];
#pragma unroll
        for (int j = 0; j < 4; ++j) {
            const int s = s0 + 8 * (4 * h + j);
            uint4 w;
            w.x = f2bf_pk(sr[2 * j].x, sr[2 * j].y);
            w.y = f2bf_pk(sr[2 * j].z, sr[2 * j].w);
            w.z = f2bf_pk(sr[2 * j + 1].x, sr[2 * j + 1].y);
            w.w = f2bf_pk(sr[2 * j + 1].z, sr[2 * j + 1].w);
            const int panel = s >> 2, q = s & 3;
            *(uint4*)&dbuf[panel * 2048 + r * 64 + (q ^ xr) * 16] = w;
        }
    };

    f32x16 acc[4];
    bf16x8 b0f[8], b1f[8];
    auto loadB = [&](bf16x8* dst, int kt) {
#pragma unroll
        for (int nt = 0; nt < 4; ++nt)
#pragma unroll
            for (int ks = 0; ks < 2; ++ks)
                dst[nt * 2 + ks] =
                    *(const bf16x8*)(bfbase + nt * 32768 + (kt * 2 + ks) * 1024);
    };
    auto computeStep = [&](const char* abuf, int kt, const bf16x8* bfr) {
        bf16x8 af[2];
#pragma unroll
        for (int ks = 0; ks < 2; ++ks) {
            const int q = (2 * ks + g) ^ ((l31 >> 2) & 3);
            af[ks] = *(const bf16x8*)&abuf[kt * 2048 + l31 * 64 + q * 16];
        }
        __builtin_amdgcn_s_setprio(1);
#pragma unroll
        for (int ks = 0; ks < 2; ++ks)
#pragma unroll
            for (int nt = 0; nt < 4; ++nt)
                acc[nt] = __builtin_amdgcn_mfma_f32_32x32x16_bf16(
                    af[ks], bfr[nt * 2 + ks], acc[nt], 0, 0, 0);
        __builtin_amdgcn_s_setprio(0);
    };

#pragma unroll
    for (int nt = 0; nt < 4; ++nt) acc[nt] = (f32x16)(0.f);

    // prologue: stage tile 0 (both halves), then the per-tile barrier
    issueA(0, 0); writeA(0, 0);
    issueA(0, 1); writeA(0, 1);
    __syncthreads();

    for (int i = 0; i < NTILE; ++i) {
        const char* abuf = As[i & 1];
        const bool pf = (i + 1 < NTILE);

        if (pf) issueA(i + 1, 0);        // half0 loads fly during K-loop 1st half
        loadB(b0f, 0);
#pragma unroll
        for (int kt = 0; kt < 8; kt += 2) {
            loadB(b1f, kt + 1);
            computeStep(abuf, kt, b0f);
            loadB(b0f, kt + 2);          // kt=6 loads kt=8 for 2nd half
            computeStep(abuf, kt + 1, b1f);
        }
        if (pf) { writeA(i + 1, 0); issueA(i + 1, 1); }
#pragma unroll
        for (int kt = 8; kt < 16; kt += 2) {
            loadB(b1f, kt + 1);
            computeStep(abuf, kt, b0f);
            if (kt + 2 < 16) loadB(b0f, kt + 2);
            computeStep(abuf, kt + 1, b1f);
        }
        if (pf) writeA(i + 1, 1);

        // ---- epilogue tile i: tanh + V-dot into v[16] ----
        float v[16];
#pragma unroll
        for (int k = 0; k < 16; ++k) v[k] = 0.f;
#pragma unroll
        for (int nt = 0; nt < 4; ++nt)
#pragma unroll
            for (int rr = 0; rr < 16; ++rr)
                v[rr] = fmaf(vwv[nt],
                             tanh_from_x2(fmaf(2.0f, acc[nt][rr], phv2[nt])),
                             v[rr]);
#pragma unroll
        for (int nt = 0; nt < 4; ++nt) acc[nt] = (f32x16)(0.f);

        // multi-value tree over the 16-lane groups; after 4 stages lane p
        // holds idx p&15 (partial over 16 lanes), butterfly pb=16 completes.
#pragma unroll
        for (int st = 0; st < 4; ++st) {
            const int pb = 1 << st;
            const bool hi = (l31 & pb) != 0;
#pragma unroll
            for (int j = 0; j < (8 >> st); ++j) {
                const float a = v[2 * j];
                const float c = v[2 * j + 1];
                const float keep = hi ? c : a;
                const float send = hi ? a : c;
                v[j] = keep + __shfl_xor(send, pb);
            }
        }
        v[0] += __shfl_xor(v[0], 16);

        // identity-order gather: dest lane d<32 wants idx r=(d&3)|((d>>3)<<2)
        // from g=(d>>2)&1 half; rows = (r&3)+8*(r>>2)+4*g. One ascending
        // contiguous 128 B store per wave (lanes 0..31).
        const int srcl = ((lane & 3) | (((lane >> 3) & 3) << 2)) +
                         32 * ((lane >> 2) & 1);
        const float out = __shfl(v[0], srcl);
        if (lane < 32)
            lpart[(size_t)(uh * 4 + widx) * (B_ * T_) + (size_t)b * T_ +
                  tg * (32 * NTILE) + i * 32 + lane] = out;
        __syncthreads();   // all reads of As[(i+1)&1] (tile i-1) done; safe
    }
}

// K3: fused softmax + attn-write + context accumulation. grid (8 seg, B),
// block 512 (r4's proven form). Sums the 8 logit partial slots per t (stride
// B*T, coalesced, L2-hot), computes softmax, writes its own attn t-slice,
// then atomically accumulates its 128-t context contribution into out_ctx.
__global__ __launch_bounds__(512) void ctx_kernel(
    const float* __restrict__ feat, const float* __restrict__ lpart,
    float* __restrict__ attn, float* __restrict__ ctx_out) {
    const int b   = blockIdx.y;
    const int seg = blockIdx.x;
    const int tid = threadIdx.x;
    __shared__ float wls[1024];
    __shared__ float redm[8];
    __shared__ float reds[8];

    float v[2];
    float mx = -3.4e38f;
#pragma unroll
    for (int j = 0; j < 2; ++j) {
        const int t = b * T_ + tid + 512 * j;
        float s0 = 0.f, s1 = 0.f;
#pragma unroll
        for (int sl = 0; sl < 4; ++sl) {
            s0 += lpart[(size_t)(2 * sl) * (B_ * T_) + t];
            s1 += lpart[(size_t)(2 * sl + 1) * (B_ * T_) + t];
        }
        v[j] = s0 + s1;
        mx = fmaxf(mx, v[j]);
    }
#pragma unroll
    for (int off = 32; off > 0; off >>= 1) mx = fmaxf(mx, __shfl_xor(mx, off));
    if ((tid & 63) == 0) redm[tid >> 6] = mx;
    __syncthreads();
    mx = fmaxf(fmaxf(fmaxf(redm[0], redm[1]), fmaxf(redm[2], redm[3])),
               fmaxf(fmaxf(redm[4], redm[5]), fmaxf(redm[6], redm[7])));
    float s = 0.f;
#pragma unroll
    for (int j = 0; j < 2; ++j) {
        v[j] = __expf(v[j] - mx);
        s += v[j];
    }
#pragma unroll
    for (int off = 32; off > 0; off >>= 1) s += __shfl_xor(s, off);
    if ((tid & 63) == 0) reds[tid >> 6] = s;
    __syncthreads();
    s = ((reds[0] + reds[1]) + (reds[2] + reds[3])) +
        ((reds[4] + reds[5]) + (reds[6] + reds[7]));
    const float inv = 1.0f / s;
    wls[tid]       = v[0] * inv;
    wls[tid + 512] = v[1] * inv;
    __syncthreads();

    // attn write: own slice only
    if (tid < 128) attn[b * T_ + seg * 128 + tid] = wls[seg * 128 + tid];

    // context over this block's 128 t (4 quarters of 32 t)
    const int q  = tid >> 7;
    const int d4 = (tid & 127) * 4;
    const int t0 = seg * 128 + q * 32;
    const float* fb = feat + ((size_t)(b * T_ + t0)) * D_ + d4;
    const float* wb = &wls[t0];
    float4 acc = {0.f, 0.f, 0.f, 0.f};
#pragma unroll 4
    for (int t = 0; t < 32; ++t) {
        const float w  = wb[t];
        const float4 f = *(const float4*)&fb[(size_t)t * D_];
        acc.x = fmaf(w, f.x, acc.x);
        acc.y = fmaf(w, f.y, acc.y);
        acc.z = fmaf(w, f.z, acc.z);
        acc.w = fmaf(w, f.w, acc.w);
    }
    float* dst = ctx_out + b * D_ + d4;
    atomicAdd(dst + 0, acc.x);
    atomicAdd(dst + 1, acc.y);
    atomicAdd(dst + 2, acc.z);
    atomicAdd(dst + 3, acc.w);
}

extern "C" void kernel_launch(void* const* d_in, const int* in_sizes, int n_in,
                              void* d_out, int out_size, void* d_ws, size_t ws_size,
                              hipStream_t stream) {
    const float* feat   = (const float*)d_in[0];
    const float* hidden = (const float*)d_in[1];
    const float* W1w    = (const float*)d_in[2];
    const float* W1b    = (const float*)d_in[3];
    const float* W2w    = (const float*)d_in[4];
    const float* W2b    = (const float*)d_in[5];
    const float* Vw     = (const float*)d_in[6];
    // V_b cancels in softmax and doesn't affect context.

    float* out_ctx  = (float*)d_out;             // [B,D]
    float* out_attn = out_ctx + B_ * D_;         // [B,T]

    unsigned short* W1F = (unsigned short*)d_ws;             // U*D bf16 = 1 MB
    float* ph     = (float*)(W1F + (size_t)U_ * D_);         // B*U
    float* lpart  = ph + B_ * U_;                            // 8*B*T = 2 MB

    prep_kernel<<<512, 256, 0, stream>>>(W1w, hidden, W2w, W2b, W1b, W1F, ph,
                                         out_ctx);
    logits_mfma_kernel<<<dim3(8, B_), 256, 0, stream>>>(feat, W1F, ph, Vw,
                                                        lpart);
    ctx_kernel<<<dim3(8, B_), 512, 0, stream>>>(feat, lpart, out_attn, out_ctx);
}

// Round 9
// 303.832 us; speedup vs baseline: 2.4339x; 2.4339x over previous
//
#include <hip/hip_runtime.h>
#include <math.h>

#define B_ 64
#define T_ 1024
#define D_ 512
#define U_ 1024

typedef __bf16 bf16x8 __attribute__((ext_vector_type(8)));
typedef float f32x16 __attribute__((ext_vector_type(16)));
typedef unsigned int u32;

// tanh(x) given x2 = 2x, pre-clamped: 1 - 2/(1+e^{x2}). Sign-correct both
// tails; clamp +-18 keeps tanh exact to <1e-7. 3 VALU + 2 trans.
__device__ __forceinline__ float tanh_from_x2(float x2) {
    const float xc = __builtin_amdgcn_fmed3f(x2, -18.f, 18.f);
    const float e  = __expf(xc);
    const float r  = __builtin_amdgcn_rcpf(e + 1.0f);
    return fmaf(-2.0f, r, 1.0f);
}

// pack two f32 -> two bf16 (round-half-up): 2 adds + 1 v_perm
__device__ __forceinline__ u32 f2bf_pk(float lo, float hi) {
    u32 a = __float_as_uint(lo) + 0x8000u;
    u32 b = __float_as_uint(hi) + 0x8000u;
    return __builtin_amdgcn_perm(b, a, 0x07060302u);
}

// K_prep: blocks [0,256): W1 [D][U] fp32 -> W1F in MFMA-fragment order:
//   frag=(ut*16+kt)*2+ks holds B-frag for u-tile ut (32 u), k=kt*32+ks*16;
//   slot (frag,lane) = 8 bf16: u=ut*32+(lane&31), k0=kt*32+ks*16+(lane>>5)*8.
// blocks [256,512): ph[b][u] = hidden·W2 + W2_b + W1_b.
__global__ __launch_bounds__(256) void prep_kernel(
    const float* __restrict__ W1, const float* __restrict__ hidden,
    const float* __restrict__ W2, const float* __restrict__ W2b,
    const float* __restrict__ W1b,
    unsigned short* __restrict__ W1F, float* __restrict__ ph) {
    if (blockIdx.x < 256) {
        const int gid  = blockIdx.x * 256 + threadIdx.x;  // 0..65535
        const int lane = gid & 63;
        const int frag = gid >> 6;                        // 0..1023
        const int ks = frag & 1;
        const int kt = (frag >> 1) & 15;
        const int ut = frag >> 5;
        const int u  = ut * 32 + (lane & 31);
        const int k0 = kt * 32 + ks * 16 + (lane >> 5) * 8;
        float f[8];
#pragma unroll
        for (int j = 0; j < 8; ++j) f[j] = W1[(size_t)(k0 + j) * U_ + u];
        uint4 w;
        w.x = f2bf_pk(f[0], f[1]);
        w.y = f2bf_pk(f[2], f[3]);
        w.z = f2bf_pk(f[4], f[5]);
        w.w = f2bf_pk(f[6], f[7]);
        *(uint4*)&W1F[(size_t)gid * 8] = w;
    } else {
        const int bx = blockIdx.x - 256;
        const int u  = (bx & 3) * 256 + threadIdx.x;
        const int b  = bx >> 2;
        const float* h = hidden + b * D_;
        float acc = 0.f;
#pragma unroll 8
        for (int d = 0; d < D_; ++d) acc = fmaf(h[d], W2[(size_t)d * U_ + u], acc);
        ph[b * U_ + u] = acc + W2b[u] + W1b[u];
    }
}

// K2: fused bf16 32x32x16-MFMA GEMM + tanh + V-dot. r7's proven form (102 µs):
// 2048 blocks (one uh per block, latency-bound regime favors the bigger grid),
// 4 waves x (64t x 128u), ONE barrier, register shfl-tree epilogue +
// identity-order gather + one ascending-contiguous 256 B store per wave.
// r8 lesson: adding reg-staged cross-tile pipelining spills (FETCH 955 MB);
// do NOT raise register liveness here.
__global__ __launch_bounds__(256, 2) void logits_mfma_kernel(
    const float* __restrict__ feat,          // [B,T,D] fp32
    const unsigned short* __restrict__ W1F,  // fragment-order bf16
    const float* __restrict__ ph,            // [B,U] biases folded
    const float* __restrict__ Vw,            // [U]
    float* __restrict__ lpart) {             // [8][B][T] partials
    __shared__ __align__(16) char As[65536];  // 16 panels x 64 rows x 64 B

    const int tid  = threadIdx.x;
    const int gx   = blockIdx.x;        // uh fastest: A-sharing pair co-dispatch
    const int uh   = gx & 1;
    const int tt   = gx >> 1;
    const int b    = blockIdx.y;
    const int t0   = tt * 64;
    const int lane = tid & 63;
    const int widx = tid >> 6;          // 0..3
    const int l31 = lane & 31, g = lane >> 5;

    // ---- stage A once: feat[b, t0..t0+64, :] fp32 -> bf16 swizzled panels ----
    {
        const int r  = tid >> 2;       // 0..63
        const int s0 = tid & 3;
        const float* src = feat + ((size_t)(b * T_ + t0 + r)) * D_;
        const int xr = (r >> 2) & 3;
#pragma unroll
        for (int i = 0; i < 16; ++i) {
            const int s = s0 + 4 * i;            // 16B slot in row
            const float4 v0 = *(const float4*)(src + s * 8);
            const float4 v1 = *(const float4*)(src + s * 8 + 4);
            uint4 w;
            w.x = f2bf_pk(v0.x, v0.y);
            w.y = f2bf_pk(v0.z, v0.w);
            w.z = f2bf_pk(v1.x, v1.y);
            w.w = f2bf_pk(v1.z, v1.w);
            const int panel = s >> 2, q = s & 3;
            *(uint4*)&As[panel * 4096 + r * 64 + (q ^ xr) * 16] = w;
        }
    }
    __syncthreads();   // the ONLY barrier in this kernel

    // B frag base for the wave's u-strip: u0 = uh*512 + widx*128 (4 u-tiles)
    const char* bfbase = (const char*)W1F +
                         (size_t)((uh * 16 + widx * 4)) * 32768 + lane * 16;

    f32x16 acc[2][4];
    bf16x8 b0[8], b1[8];

    auto loadB = [&](bf16x8* dst, int kt) {
#pragma unroll
        for (int nt = 0; nt < 4; ++nt)
#pragma unroll
            for (int ks = 0; ks < 2; ++ks)
                dst[nt * 2 + ks] =
                    *(const bf16x8*)(bfbase + nt * 32768 + (kt * 2 + ks) * 1024);
    };

    auto computeStep = [&](int kt, const bf16x8* bfr) {
        bf16x8 af[2][2];   // [ks][mt]
#pragma unroll
        for (int ks = 0; ks < 2; ++ks)
#pragma unroll
            for (int mt = 0; mt < 2; ++mt) {
                const int rr = mt * 32 + l31;
                const int q  = (2 * ks + g) ^ ((rr >> 2) & 3);
                af[ks][mt] = *(const bf16x8*)&As[kt * 4096 + rr * 64 + q * 16];
            }
        __builtin_amdgcn_s_setprio(1);
#pragma unroll
        for (int ks = 0; ks < 2; ++ks)
#pragma unroll
            for (int mt = 0; mt < 2; ++mt)
#pragma unroll
                for (int nt = 0; nt < 4; ++nt)
                    acc[mt][nt] = __builtin_amdgcn_mfma_f32_32x32x16_bf16(
                        af[ks][mt], bfr[nt * 2 + ks], acc[mt][nt], 0, 0, 0);
        __builtin_amdgcn_s_setprio(0);
    };

#pragma unroll
    for (int mt = 0; mt < 2; ++mt)
#pragma unroll
        for (int nt = 0; nt < 4; ++nt) acc[mt][nt] = (f32x16)(0.f);

    loadB(b0, 0);
    for (int kt = 0; kt < 16; kt += 2) {
        loadB(b1, kt + 1);
        computeStep(kt, b0);
        if (kt + 2 < 16) loadB(b0, kt + 2);
        computeStep(kt + 1, b1);
    }

    // ---- fused epilogue: tanh + V-dot into flat v[32] ----
    float v[32];
#pragma unroll
    for (int i = 0; i < 32; ++i) v[i] = 0.f;

#pragma unroll
    for (int nt = 0; nt < 4; ++nt) {
        const int u = uh * 512 + widx * 128 + nt * 32 + l31;
        const float phv2 = 2.0f * ph[b * U_ + u];
        const float vw   = Vw[u];
#pragma unroll
        for (int mt = 0; mt < 2; ++mt)
#pragma unroll
            for (int r = 0; r < 16; ++r) {
                const float th =
                    tanh_from_x2(fmaf(2.0f, acc[mt][nt][r], phv2));
                v[mt * 16 + r] = fmaf(vw, th, v[mt * 16 + r]);
            }
    }

    // ---- multi-value tree reduce over the 32 lanes of each half ----
    // After 5 stages lane p holds the full u-strip sum for flat index
    // p&31 => row(p) = (p&3) + 8*((p>>2)&3) + 4*(p>>5) + 32*((p>>4)&1).
#pragma unroll
    for (int s = 0; s < 5; ++s) {
        const int pb = 1 << s;
        const bool hi = (l31 & pb) != 0;
#pragma unroll
        for (int j = 0; j < (16 >> s); ++j) {
            const float a = v[2 * j];
            const float c = v[2 * j + 1];
            const float keep = hi ? c : a;
            const float send = hi ? a : c;
            v[j] = keep + __shfl_xor(send, pb);
        }
    }

    // ---- identity-order gather + ONE ascending-contiguous 256 B store.
    // Dest lane r wants the value of lane p with row(p)=r:
    //   l31(p) = (r&3) | (((r>>3)&3)<<2) | (((r>>5)&1)<<4), g(p)=(r>>2)&1.
    const int src = ((lane & 3) | (((lane >> 3) & 3) << 2) |
                     (((lane >> 5) & 1) << 4)) + 32 * ((lane >> 2) & 1);
    const float out = __shfl(v[0], src);
    lpart[((size_t)(uh * 4 + widx)) * (B_ * T_) + (size_t)b * T_ + t0 + lane] =
        out;
}

// K3: fused softmax + attn-write + context, ATOMIC-FREE (v9).
// Previous form ended in 1M contended fp32 atomicAdds (512 blk x 512 thr x 4,
// 32-way per address). New decomposition: grid (8 ds, B), block (ds,b) owns
// d-slice [ds*64, ds*64+64) across ALL t -> each block writes its ctx slice
// directly, no atomics, no zero-init. Softmax stats recomputed per block
// (lpart row = 8 KB, L2-hot). Context loop: 8 t-chunks x 64 d lanes; wave
// reads 64 consecutive d (256 B coalesced); wls[t] is wave-uniform (LDS
// broadcast). LDS-reduce the 8 chunk partials, 64 threads write the slice.
__global__ __launch_bounds__(512) void ctx_kernel(
    const float* __restrict__ feat, const float* __restrict__ lpart,
    float* __restrict__ attn, float* __restrict__ ctx_out) {
    const int b   = blockIdx.y;
    const int ds  = blockIdx.x;     // 0..7: 64-d slice
    const int tid = threadIdx.x;
    __shared__ float wls[1024];
    __shared__ float redm[8];
    __shared__ float reds[8];
    __shared__ float cpart[8][64];

    float v[2];
    float mx = -3.4e38f;
#pragma unroll
    for (int j = 0; j < 2; ++j) {
        const int t = b * T_ + tid + 512 * j;
        float s0 = 0.f, s1 = 0.f;
#pragma unroll
        for (int sl = 0; sl < 4; ++sl) {
            s0 += lpart[(size_t)(2 * sl) * (B_ * T_) + t];
            s1 += lpart[(size_t)(2 * sl + 1) * (B_ * T_) + t];
        }
        v[j] = s0 + s1;
        mx = fmaxf(mx, v[j]);
    }
#pragma unroll
    for (int off = 32; off > 0; off >>= 1) mx = fmaxf(mx, __shfl_xor(mx, off));
    if ((tid & 63) == 0) redm[tid >> 6] = mx;
    __syncthreads();
    mx = fmaxf(fmaxf(fmaxf(redm[0], redm[1]), fmaxf(redm[2], redm[3])),
               fmaxf(fmaxf(redm[4], redm[5]), fmaxf(redm[6], redm[7])));
    float s = 0.f;
#pragma unroll
    for (int j = 0; j < 2; ++j) {
        v[j] = __expf(v[j] - mx);
        s += v[j];
    }
#pragma unroll
    for (int off = 32; off > 0; off >>= 1) s += __shfl_xor(s, off);
    if ((tid & 63) == 0) reds[tid >> 6] = s;
    __syncthreads();
    s = ((reds[0] + reds[1]) + (reds[2] + reds[3])) +
        ((reds[4] + reds[5]) + (reds[6] + reds[7]));
    const float inv = 1.0f / s;
    wls[tid]       = v[0] * inv;
    wls[tid + 512] = v[1] * inv;
    __syncthreads();

    // attn write: one block per b (ds==0) writes the full row
    if (ds == 0) {
        attn[b * T_ + tid]       = wls[tid];
        attn[b * T_ + tid + 512] = wls[tid + 512];
    }

    // context: thread (tc, dl) accumulates t in [tc*128, tc*128+128) for
    // d = ds*64 + dl. Wave = 64 consecutive d -> 256 B coalesced per t.
    const int tc = tid >> 6;        // 0..7
    const int dl = tid & 63;
    const float* fb =
        feat + ((size_t)(b * T_ + tc * 128)) * D_ + ds * 64 + dl;
    const float* wb = &wls[tc * 128];
    float acc = 0.f;
#pragma unroll 4
    for (int t = 0; t < 128; ++t)
        acc = fmaf(wb[t], fb[(size_t)t * D_], acc);
    cpart[tc][dl] = acc;
    __syncthreads();
    if (tid < 64) {
        float cs = 0.f;
#pragma unroll
        for (int k = 0; k < 8; ++k) cs += cpart[k][tid];
        ctx_out[b * D_ + ds * 64 + tid] = cs;
    }
}

extern "C" void kernel_launch(void* const* d_in, const int* in_sizes, int n_in,
                              void* d_out, int out_size, void* d_ws, size_t ws_size,
                              hipStream_t stream) {
    const float* feat   = (const float*)d_in[0];
    const float* hidden = (const float*)d_in[1];
    const float* W1w    = (const float*)d_in[2];
    const float* W1b    = (const float*)d_in[3];
    const float* W2w    = (const float*)d_in[4];
    const float* W2b    = (const float*)d_in[5];
    const float* Vw     = (const float*)d_in[6];
    // V_b cancels in softmax and doesn't affect context.

    float* out_ctx  = (float*)d_out;             // [B,D]
    float* out_attn = out_ctx + B_ * D_;         // [B,T]

    unsigned short* W1F = (unsigned short*)d_ws;             // U*D bf16 = 1 MB
    float* ph     = (float*)(W1F + (size_t)U_ * D_);         // B*U
    float* lpart  = ph + B_ * U_;                            // 8*B*T = 2 MB

    prep_kernel<<<512, 256, 0, stream>>>(W1w, hidden, W2w, W2b, W1b, W1F, ph);
    logits_mfma_kernel<<<dim3(32, B_), 256, 0, stream>>>(feat, W1F, ph, Vw,
                                                         lpart);
    ctx_kernel<<<dim3(8, B_), 512, 0, stream>>>(feat, lpart, out_attn, out_ctx);
}